// Round 8
// baseline (594.367 us; speedup 1.0000x reference)
//
#include <hip/hip_runtime.h>
#include <hip/hip_bf16.h>

// out[1,512] = sum_rows(relu(concat(v0,v1) @ W.T + b))
// Barrier-free streaming (R3 structure, spill- and overfetch-fixed):
//   W tile (64 cols x 512 K, bf16, XOR-swizzled) resident in LDS per block.
//   A: global->reg f32 depth-2, cvt->bf16, per-wave 32-row strip.
//   Grid 512 = exactly all-resident (2 blocks/CU by LDS) => the 8 col-block
//   siblings of each slot are co-resident on one XCD => A served once from
//   HBM, 7x from L2. No barriers in the main loop; cross-panel prefetch.

typedef __bf16 bf16x8 __attribute__((ext_vector_type(8)));
typedef float  f32x4  __attribute__((ext_vector_type(4)));

#define PROWS 256      // rows per block-panel (8 waves x 32)
#define NSLOT 64       // independent row streams (512 blocks / 8 cb)
#define NK    16       // 512 / 32

static __device__ __forceinline__ bf16x8 pack8(float4 a, float4 b) {
    bf16x8 o;
    o[0] = (__bf16)a.x; o[1] = (__bf16)a.y; o[2] = (__bf16)a.z; o[3] = (__bf16)a.w;
    o[4] = (__bf16)b.x; o[5] = (__bf16)b.y; o[6] = (__bf16)b.z; o[7] = (__bf16)b.w;
    return o;
}

__global__ __launch_bounds__(512) void fused_gemm_pool(
    const float* __restrict__ v0, const float* __restrict__ v1,
    const float* __restrict__ W,  const float* __restrict__ b,
    float* __restrict__ partial, int N, int numPanels)
{
    __shared__ unsigned short Ws[64 * 512];   // 64 KB bf16, chunk-swizzled
    __shared__ float ldsPart[8][64];

    int bid  = blockIdx.x;          // 0..511
    int xcd  = bid & 7;
    int idx  = bid >> 3;            // 0..63
    int cb   = idx & 7;             // col-block 0..7 (siblings share XCD)
    int sIn  = idx >> 3;            // 0..7
    int slot = xcd * 8 + sIn;       // 0..63

    int tid = threadIdx.x, wid = tid >> 6, lane = tid & 63;
    int l15 = lane & 15, l4 = lane >> 4, s3 = l15 & 7;

    // ---- stage W tile once: 64 cols x 512 K, f32 -> bf16, swizzled chunks ----
    #pragma unroll
    for (int i = 0; i < 8; ++i) {
        int m = tid + i * 512;            // 4096 chunks of 8 elems
        int row = m >> 6, ch = m & 63;    // row = W output col, ch = k-chunk
        const float* ws = W + (size_t)(cb * 64 + row) * 512 + ch * 8;
        float4 f0 = *(const float4*)ws;
        float4 f1 = *(const float4*)(ws + 4);
        *(bf16x8*)&Ws[row * 512 + ((ch ^ (row & 7)) * 8)] = pack8(f0, f1);
    }
    __syncthreads();                // the only barrier before the final reduce

    float bv[4];
    #pragma unroll
    for (int nf = 0; nf < 4; ++nf) bv[nf] = b[cb * 64 + nf * 16 + l15];

    float csum[4] = {0.f, 0.f, 0.f, 0.f};

    // A offsets (f32 element units; clamped rows stay in-bounds, masked later)
    int r0 = slot * PROWS + wid * 32;
    int off0 = min(r0 + l15,      N - 1) * 256 + l4 * 8;
    int off1 = min(r0 + 16 + l15, N - 1) * 256 + l4 * 8;

    float4 st[2][4];                // depth-2 A staging (f32)
    st[0][0] = *(const float4*)(v0 + off0);
    st[0][1] = *(const float4*)(v0 + off0 + 4);
    st[0][2] = *(const float4*)(v0 + off1);
    st[0][3] = *(const float4*)(v0 + off1 + 4);

    for (int p = slot; p < numPanels; p += NSLOT) {
        int rb0 = p * PROWS + wid * 32;

        f32x4 acc[2][4];
        #pragma unroll
        for (int mf = 0; mf < 2; ++mf)
            #pragma unroll
            for (int nf = 0; nf < 4; ++nf)
                acc[mf][nf] = (f32x4){0.f, 0.f, 0.f, 0.f};

        #pragma unroll
        for (int kt = 0; kt < NK; ++kt) {
            const int cur = kt & 1;
            if (kt < NK - 1) {
                // prefetch next K-step (same panel)
                const float* s2 = (kt + 1 < 8) ? v0 : v1;
                const int k0 = ((kt + 1) & 7) * 32;
                st[cur ^ 1][0] = *(const float4*)(s2 + off0 + k0);
                st[cur ^ 1][1] = *(const float4*)(s2 + off0 + k0 + 4);
                st[cur ^ 1][2] = *(const float4*)(s2 + off1 + k0);
                st[cur ^ 1][3] = *(const float4*)(s2 + off1 + k0 + 4);
            } else {
                // prefetch next panel's kt=0 (harmless clamped load past end)
                int np = p + NSLOT;
                int nr = np * PROWS + wid * 32;
                off0 = min(nr + l15,      N - 1) * 256 + l4 * 8;
                off1 = min(nr + 16 + l15, N - 1) * 256 + l4 * 8;
                st[0][0] = *(const float4*)(v0 + off0);
                st[0][1] = *(const float4*)(v0 + off0 + 4);
                st[0][2] = *(const float4*)(v0 + off1);
                st[0][3] = *(const float4*)(v0 + off1 + 4);
            }
            bf16x8 af0 = pack8(st[cur][0], st[cur][1]);
            bf16x8 af1 = pack8(st[cur][2], st[cur][3]);
            #pragma unroll
            for (int nf = 0; nf < 4; ++nf) {
                bf16x8 bf = *(const bf16x8*)
                    &Ws[(nf * 16 + l15) * 512 + (((kt * 4 + l4) ^ s3) * 8)];
                acc[0][nf] = __builtin_amdgcn_mfma_f32_16x16x32_bf16(af0, bf, acc[0][nf], 0, 0, 0);
                acc[1][nf] = __builtin_amdgcn_mfma_f32_16x16x32_bf16(af1, bf, acc[1][nf], 0, 0, 0);
            }
        }

        // epilogue: bias + relu + row-mask -> per-lane column partials
        #pragma unroll
        for (int nf = 0; nf < 4; ++nf) {
            float bb = bv[nf];
            #pragma unroll
            for (int mf = 0; mf < 2; ++mf) {
                int rbase = rb0 + mf * 16 + l4 * 4;
                #pragma unroll
                for (int j = 0; j < 4; ++j) {
                    float v = fmaxf(acc[mf][nf][j] + bb, 0.f);
                    if (rbase + j < N) csum[nf] += v;
                }
            }
        }
    }

    // cross-lane column reduce: lanes l, l^16, l^32, l^48 share a column
    #pragma unroll
    for (int nf = 0; nf < 4; ++nf) {
        float s = csum[nf];
        s += __shfl_xor(s, 16);
        s += __shfl_xor(s, 32);
        if (lane < 16) ldsPart[wid][nf * 16 + lane] = s;
    }
    __syncthreads();
    if (tid < 64) {
        float s = 0.f;
        #pragma unroll
        for (int w = 0; w < 8; ++w) s += ldsPart[w][tid];
        partial[(size_t)slot * 512 + cb * 64 + tid] = s;
    }
}

__global__ void reduce_partials(const float* __restrict__ partial,
                                float* __restrict__ out)
{
    int c = threadIdx.x;
    if (c < 512) {
        float s = 0.f;
        for (int i = 0; i < NSLOT; ++i) s += partial[(size_t)i * 512 + c];
        out[c] = s;
    }
}

extern "C" void kernel_launch(void* const* d_in, const int* in_sizes, int n_in,
                              void* d_out, int out_size, void* d_ws, size_t ws_size,
                              hipStream_t stream)
{
    const float* v0 = (const float*)d_in[0];
    const float* v1 = (const float*)d_in[1];
    const float* W  = (const float*)d_in[2];
    const float* b  = (const float*)d_in[3];
    float* out      = (float*)d_out;
    float* partial  = (float*)d_ws;            // 64*512*4 = 128 KB

    int N = in_sizes[0] / 256;
    int numPanels = (N + PROWS - 1) / PROWS;

    fused_gemm_pool<<<dim3(512), dim3(512), 0, stream>>>(
        v0, v1, W, b, partial, N, numPanels);
    reduce_partials<<<dim3(1), dim3(512), 0, stream>>>(partial, out);
}

// Round 9
// 468.312 us; speedup vs baseline: 1.2692x; 1.2692x over previous
//
#include <hip/hip_runtime.h>
#include <hip/hip_bf16.h>

// out[1,512] = sum_rows(relu(concat(v0,v1) @ W.T + b))
// m97-faithful: BOTH operands staged via global_load_lds (A as f32 - no cvt
// in staging; cvt at fragment read). Triple-buffered LDS (A 8KB f32 +
// B 8KB bf16 per buf), ONE barrier + counted vmcnt(4) per K-step, staging
// flows continuously across row-blocks (pipeline never drains).
// 256 thr / 4 waves; wave tile 32x64; acc[2][4]=32 AGPR; target <=128 regs.

typedef __bf16 bf16x8 __attribute__((ext_vector_type(8)));
typedef float  f32x4  __attribute__((ext_vector_type(4)));
typedef unsigned short u16x4 __attribute__((ext_vector_type(4)));

#define BM 64
#define BN 128
#define NK 16            // 512 / 32
#define ABUF 8192        // 64 rows x 32 k x 4B
#define NCB 4

static __device__ __forceinline__ unsigned short f2bf(float f) {
    return __builtin_bit_cast(unsigned short, (__bf16)f);
}
static __device__ __forceinline__ bf16x8 pack8(float4 a, float4 b) {
    bf16x8 o;
    o[0] = (__bf16)a.x; o[1] = (__bf16)a.y; o[2] = (__bf16)a.z; o[3] = (__bf16)a.w;
    o[4] = (__bf16)b.x; o[5] = (__bf16)b.y; o[6] = (__bf16)b.z; o[7] = (__bf16)b.w;
    return o;
}

#define GLDS16(G, L) __builtin_amdgcn_global_load_lds(                       \
    (const __attribute__((address_space(1))) void*)(G),                     \
    (__attribute__((address_space(3))) void*)(L), 16, 0, 0)

__global__ void conv_w_bf16(const float* __restrict__ W, unsigned short* __restrict__ Wb) {
    int idx = (blockIdx.x * blockDim.x + threadIdx.x) * 4;   // 512*512, exact
    float4 f = *(const float4*)(W + idx);
    u16x4 p;
    p[0] = f2bf(f.x); p[1] = f2bf(f.y); p[2] = f2bf(f.z); p[3] = f2bf(f.w);
    *(u16x4*)(Wb + idx) = p;
}

template<bool WBF16>
__global__ __launch_bounds__(256) void fused_gemm_pool(
    const float* __restrict__ v0, const float* __restrict__ v1,
    const unsigned short* __restrict__ Wb, const float* __restrict__ Wf,
    const float* __restrict__ b,
    float* __restrict__ partial, int N, int numRB, int slots)
{
    constexpr int BB = WBF16 ? 8192 : 16384;   // B buffer bytes
    __shared__ char smem[3 * (ABUF + BB)];
    __shared__ float ldsPart[4][64];

    int bid  = blockIdx.x;
    int xcd  = bid & 7;
    int cb   = (bid >> 3) & 3;       // col-block (siblings share XCD)
    int grp  = bid >> 5;
    int slot = grp * 8 + xcd;        // 0..slots-1

    int tid = threadIdx.x, wid = tid >> 6, lane = tid & 63;
    int wr = wid & 1, wc = wid >> 1, l15 = lane & 15, l4 = lane >> 4;

    // ---- A staging constants: 2 chunks/thread, chunk m=(row<<3)|c ----
    int arow0 = tid >> 3,        ac0 = tid & 7;
    int arow1 = (tid + 256) >> 3, ac1 = (tid + 256) & 7;
    int aoff0 = (ac0 ^ (arow0 & 7)) * 4;       // swizzled k-quad (f32 elems)
    int aoff1 = (ac1 ^ (arow1 & 7)) * 4;

    // ---- B staging constants ----
    int bS0, bS1, cS0, cS1, cS2, cS3;
    {
        int m0 = tid, m1 = tid + 256;
        // bf16 layout: chunk m=(col<<2)|c, 4 chunks of 8 bf16 per col
        bS0 = (cb * 128 + (m0 >> 2)) * 512 + (((m0 & 3) ^ (((m0 >> 2) >> 1) & 3)) * 8);
        bS1 = (cb * 128 + (m1 >> 2)) * 512 + (((m1 & 3) ^ (((m1 >> 2) >> 1) & 3)) * 8);
        // f32 fallback: chunk m=(col<<3)|c, 8 chunks of 4 f32 per col
        int n0 = tid, n1 = tid + 256, n2 = tid + 512, n3 = tid + 768;
        cS0 = (cb * 128 + (n0 >> 3)) * 512 + (((n0 & 7) ^ ((n0 >> 3) & 7)) * 4);
        cS1 = (cb * 128 + (n1 >> 3)) * 512 + (((n1 & 7) ^ ((n1 >> 3) & 7)) * 4);
        cS2 = (cb * 128 + (n2 >> 3)) * 512 + (((n2 & 7) ^ ((n2 >> 3) & 7)) * 4);
        cS3 = (cb * 128 + (n3 >> 3)) * 512 + (((n3 & 7) ^ ((n3 >> 3) & 7)) * 4);
    }

    // ---- fragment-read offsets (within one buffer) ----
    int offAf[2][2], offBf[4];
    #pragma unroll
    for (int mf = 0; mf < 2; ++mf) {
        int rA = wr * 32 + mf * 16 + l15;
        #pragma unroll
        for (int h = 0; h < 2; ++h)
            offAf[mf][h] = rA * 128 + (((2 * l4 + h) ^ (l15 & 7)) * 16);
    }
    #pragma unroll
    for (int nf = 0; nf < 4; ++nf) {
        int cB = wc * 64 + nf * 16 + l15;
        if constexpr (WBF16)
            offBf[nf] = cB * 64 + ((l4 ^ ((l15 >> 1) & 3)) * 16);
        else
            offBf[nf] = cB * 128;   // + per-h swizzle applied at read
    }

    float bv[4];
    #pragma unroll
    for (int nf = 0; nf < 4; ++nf) bv[nf] = b[cb * 128 + wc * 64 + nf * 16 + l15];
    float csum[4] = {0.f, 0.f, 0.f, 0.f};

    // per-rowblock A source offsets (f32 elements, row-clamped)
    int aCur0, aCur1, aNxt0, aNxt1;
    auto setA = [&](int rbx, int& a0, int& a1) {
        a0 = min(rbx * BM + arow0, N - 1) * 256 + aoff0;
        a1 = min(rbx * BM + arow1, N - 1) * 256 + aoff1;
    };

    auto stage = [&](int a0, int a1, int kt, int buf) {
        const float* srcA = (kt < 8) ? v0 : v1;
        int k0 = (kt & 7) * 32;
        char* dA = smem + buf * ABUF;
        GLDS16(srcA + a0 + k0, dA + tid * 16);
        GLDS16(srcA + a1 + k0, dA + 4096 + tid * 16);
        char* dB = smem + 3 * ABUF + buf * BB;
        if constexpr (WBF16) {
            GLDS16(Wb + bS0 + kt * 32, dB + tid * 16);
            GLDS16(Wb + bS1 + kt * 32, dB + 4096 + tid * 16);
        } else {
            GLDS16(Wf + cS0 + kt * 32, dB + tid * 16);
            GLDS16(Wf + cS1 + kt * 32, dB + 4096 + tid * 16);
            GLDS16(Wf + cS2 + kt * 32, dB + 8192 + tid * 16);
            GLDS16(Wf + cS3 + kt * 32, dB + 12288 + tid * 16);
        }
    };

    int rb = slot;
    int ph = 0;
    if (rb < numRB) {
        setA(rb, aCur0, aCur1);
        setA(rb + slots, aNxt0, aNxt1);
        stage(aCur0, aCur1, 0, 0);
        stage(aCur0, aCur1, 1, 1);
    }

    for (; rb < numRB; rb += slots) {
        f32x4 acc[2][4];
        #pragma unroll
        for (int mf = 0; mf < 2; ++mf)
            #pragma unroll
            for (int nf = 0; nf < 4; ++nf)
                acc[mf][nf] = (f32x4){0.f, 0.f, 0.f, 0.f};

        #pragma unroll
        for (int kt = 0; kt < NK; ++kt) {
            int buf = ph + (kt % 3);          if (buf >= 3) buf -= 3;
            int nbuf = ph + ((kt + 2) % 3);   if (nbuf >= 3) nbuf -= 3;

            // wait for THIS step's staging batch (leave next batch in flight),
            // then block-wide barrier (wait-before-barrier => all DMAs landed)
            if constexpr (WBF16) asm volatile("s_waitcnt vmcnt(4)" ::: "memory");
            else                 asm volatile("s_waitcnt vmcnt(6)" ::: "memory");
            __builtin_amdgcn_s_barrier();

            // issue stage for step g+2 (possibly next row-block)
            if (kt < NK - 2) stage(aCur0, aCur1, kt + 2, nbuf);
            else             stage(aNxt0, aNxt1, kt + 2 - NK, nbuf);
            __builtin_amdgcn_sched_barrier(0);

            const char* bufA = smem + buf * ABUF;
            const char* bufB = smem + 3 * ABUF + buf * BB;
            bf16x8 af[2];
            #pragma unroll
            for (int mf = 0; mf < 2; ++mf) {
                float4 h0 = *(const float4*)(bufA + offAf[mf][0]);
                float4 h1 = *(const float4*)(bufA + offAf[mf][1]);
                af[mf] = pack8(h0, h1);
            }
            bf16x8 bf[4];
            #pragma unroll
            for (int nf = 0; nf < 4; ++nf) {
                if constexpr (WBF16) {
                    bf[nf] = *(const bf16x8*)(bufB + offBf[nf]);
                } else {
                    int cB = wc * 64 + nf * 16 + l15;
                    float4 h0 = *(const float4*)(bufB + offBf[nf] + (((2 * l4 + 0) ^ (cB & 7)) * 16));
                    float4 h1 = *(const float4*)(bufB + offBf[nf] + (((2 * l4 + 1) ^ (cB & 7)) * 16));
                    bf[nf] = pack8(h0, h1);
                }
            }
            #pragma unroll
            for (int mf = 0; mf < 2; ++mf)
                #pragma unroll
                for (int nf = 0; nf < 4; ++nf)
                    acc[mf][nf] = __builtin_amdgcn_mfma_f32_16x16x32_bf16(
                        af[mf], bf[nf], acc[mf][nf], 0, 0, 0);
        }
        ph = ph + 1; if (ph >= 3) ph -= 3;    // 16 % 3 == 1
        aCur0 = aNxt0; aCur1 = aNxt1;
        setA(rb + 2 * slots, aNxt0, aNxt1);

        // epilogue overlaps the already-issued next-rb staging DMAs
        #pragma unroll
        for (int nf = 0; nf < 4; ++nf) {
            float bb = bv[nf];
            #pragma unroll
            for (int mf = 0; mf < 2; ++mf) {
                int rbase = rb * BM + wr * 32 + mf * 16 + l4 * 4;
                #pragma unroll
                for (int r = 0; r < 4; ++r) {
                    float v = fmaxf(acc[mf][nf][r] + bb, 0.f);
                    if (rbase + r < N) csum[nf] += v;
                }
            }
        }
    }

    // cross-lane column reduce: lanes l, l^16, l^32, l^48 share a column
    #pragma unroll
    for (int nf = 0; nf < 4; ++nf) {
        float s = csum[nf];
        s += __shfl_xor(s, 16);
        s += __shfl_xor(s, 32);
        if (lane < 16) ldsPart[wid][nf * 16 + lane] = s;
    }
    __syncthreads();   // also drains any outstanding tail DMAs
    if (tid < 128) {
        int wcx = tid >> 6, cw = tid & 63;
        float s = ldsPart[wcx * 2][cw] + ldsPart[wcx * 2 + 1][cw];
        partial[(size_t)slot * 512 + cb * 128 + tid] = s;
    }
}

__global__ void reduce_partials(const float* __restrict__ partial,
                                float* __restrict__ out, int slots)
{
    int c = threadIdx.x;
    if (c < 512) {
        float s = 0.f;
        for (int i = 0; i < slots; ++i) s += partial[(size_t)i * 512 + c];
        out[c] = s;
    }
}

extern "C" void kernel_launch(void* const* d_in, const int* in_sizes, int n_in,
                              void* d_out, int out_size, void* d_ws, size_t ws_size,
                              hipStream_t stream)
{
    const float* v0 = (const float*)d_in[0];
    const float* v1 = (const float*)d_in[1];
    const float* Wf = (const float*)d_in[2];
    const float* b  = (const float*)d_in[3];
    float* out      = (float*)d_out;

    int N = in_sizes[0] / 256;
    int numRB = (N + BM - 1) / BM;

    const size_t wbytes = (size_t)512 * 512 * sizeof(unsigned short);   // 512 KB
    auto pbytes = [](int s) { return (size_t)s * 512 * sizeof(float); };

    int slots; bool useWb;
    if      (ws_size >= wbytes + pbytes(192)) { slots = 192; useWb = true;  }
    else if (ws_size >= wbytes + pbytes(128)) { slots = 128; useWb = true;  }
    else if (ws_size >= wbytes + pbytes(64))  { slots = 64;  useWb = true;  }
    else                                      { slots = 128; useWb = false; } // ws>=256KB proven

    if (useWb) {
        unsigned short* Wb = (unsigned short*)d_ws;
        float* partial = (float*)((char*)d_ws + wbytes);
        conv_w_bf16<<<dim3(256), dim3(256), 0, stream>>>(Wf, Wb);
        fused_gemm_pool<true><<<dim3(slots * NCB), dim3(256), 0, stream>>>(
            v0, v1, Wb, Wf, b, partial, N, numRB, slots);
        reduce_partials<<<dim3(1), dim3(512), 0, stream>>>(partial, out, slots);
    } else {
        float* partial = (float*)d_ws;
        fused_gemm_pool<false><<<dim3(slots * NCB), dim3(256), 0, stream>>>(
            v0, v1, nullptr, Wf, b, partial, N, numRB, slots);
        reduce_partials<<<dim3(1), dim3(512), 0, stream>>>(partial, out, slots);
    }
}